// Round 15
// baseline (268.131 us; speedup 1.0000x reference)
//
#include <hip/hip_runtime.h>
#include <hip/hip_fp16.h>
#include <cstdint>

typedef _Float16 half8  __attribute__((ext_vector_type(8)));
typedef _Float16 half4v __attribute__((ext_vector_type(4)));
typedef _Float16 half2v __attribute__((ext_vector_type(2)));
typedef float    floatx4 __attribute__((ext_vector_type(4)));

// problem dims (fixed by setup_inputs)
constexpr int Bb = 4, Ss = 4096, Dd = 1024;
constexpr int Mdim = Bb * Ss;          // 16384
constexpr int Ndim = 3 * Dd;           // 3072
constexpr int Kdim = Dd;               // 1024
constexpr int CH = 256, LCH = Ss / CH; // 256 chunks of 16 steps (= MFMA frag M)

// ---------------------------------------------------------------- utils
__device__ __forceinline__ void gload_lds16(const void* g, void* l) {
  __builtin_amdgcn_global_load_lds(
      (const __attribute__((address_space(1))) uint32_t*)g,
      (__attribute__((address_space(3))) uint32_t*)l, 16, 0, 0);
}

// gate math: fw = sig(f)/(sig(f)+sig(i)) = (1+e^-i)/(2+e^-f+e^-i)
//            iw = (1+e^-f)/(2+e^-f+e^-i);  v = iw * g~(h)
__device__ __forceinline__ void gate_fv(float fg, float ig, float hg,
                                        float& fw, float& v) {
  float ef = __expf(fminf(-fg, 40.f));
  float ei = __expf(fminf(-ig, 40.f));
  float r  = __builtin_amdgcn_rcpf(2.f + ef + ei);
  fw = (1.f + ei) * r;
  float iw = (1.f + ef) * r;
  float g  = hg >= 0.f ? hg + 0.5f
                       : __builtin_amdgcn_rcpf(1.f + __expf(fminf(-hg, 40.f)));
  v = iw * g;
}

// ---------------------------------------------------------------- K0: fused x->fp16 + W transpose->fp16 (permuted)
// p(n) = (d>>6)*192 + g*64 + (d&63): each GEMM n-block gets contiguous rows
// {f,i,h} for its 64 d-channels.
__global__ __launch_bounds__(256) void cvt_k(const float* __restrict__ X,
                                             _Float16* __restrict__ X16,
                                             const float* __restrict__ W,
                                             _Float16* __restrict__ WT) {
  __shared__ float tile[32][33];
  int bid = blockIdx.x;
  if (bid < 2048) {
    const int n4 = Mdim * Kdim / 4;
    for (int i = bid * 256 + threadIdx.x; i < n4; i += 2048 * 256) {
      float4 v = ((const float4*)X)[i];
      half4v o = {(_Float16)v.x, (_Float16)v.y, (_Float16)v.z, (_Float16)v.w};
      ((half4v*)X16)[i] = o;
    }
  } else {
    int b2 = bid - 2048;
    int tx = threadIdx.x & 31, ty = threadIdx.x >> 5;  // 32 x 8
    int n0 = (b2 % 96) * 32, k0 = (b2 / 96) * 32;
#pragma unroll
    for (int j = 0; j < 4; ++j) {
      int k = ty + j * 8;
      tile[k][tx] = W[(int64_t)(k0 + k) * Ndim + n0 + tx];
    }
    __syncthreads();
#pragma unroll
    for (int j = 0; j < 4; ++j) {
      int nl = ty + j * 8;
      int n = n0 + nl;
      int g = n >> 10, d = n & 1023;
      int p = (d >> 6) * 192 + g * 64 + (d & 63);
      WT[(int64_t)p * Kdim + k0 + tx] = (_Float16)tile[tx][nl];
    }
  }
}

// ---------------------------------------------------------------- K1: 128x192 GEMM, B direct global->reg, A in LDS
// LDS was the oversubscribed pipe (~3300 cyc/CU/tile vs 1865 MFMA): B moves
// to direct global loads (one 128-B line per B-row covers the whole BK=64
// slice; all lq groups share it; panel is L2/L1-hot). LDS holds only A:
// 16 KiB x 2 buffers, XOR-swizzled. One barrier per tile (mid): each wave's
// Q0 b-wait transitively retires its A(kt+1) stage (FIFO), so after the
// barrier A(kt+1) is globally visible and cur-A is dead for the restage.
constexpr int GBM = 128, GBN = 192, GBK = 64;
constexpr int NT = Kdim / GBK;  // 16 K-tiles
constexpr int LBUF = 16384;

__global__ __launch_bounds__(512, 4) void gemm8_k(const _Float16* __restrict__ A,
                                                  const _Float16* __restrict__ BT,
                                                  _Float16* __restrict__ fv,
                                                  float* __restrict__ Fc,
                                                  float* __restrict__ Hc) {
  extern __shared__ char lds[];  // 32768 bytes
  const int tid = threadIdx.x;
  const int wid = tid >> 6, lane = tid & 63;
  const int wm = wid >> 2, wn = wid & 3;  // 2 M-groups x 4 N-groups
  const int l15 = lane & 15, lq = lane >> 4;

  // XCD-aware swizzle (2048 % 8 == 0 -> bijective)
  int wg = blockIdx.x;
  wg = (wg & 7) * 256 + (wg >> 3);
  const int m0 = (wg >> 4) * GBM;       // 128 m-panels
  const int d0 = (wg & 15) * 64;        // 16 d-panels

  // A LDS read byte-offsets (ks=0); ks=1 = offset ^ 64 (XOR-swizzle property)
  int aO[4];
#pragma unroll
  for (int mi = 0; mi < 4; ++mi) {
    int r = wm * 64 + mi * 16 + l15;
    aO[mi] = r * 128 + ((lq ^ (r & 7)) << 4);
  }

  // A staging: thread -> (row srr + 64*round, slot ss); dest linear,
  // source column pre-inverse-swizzled (rule #21)
  const int srr = (wid << 3) + (lane >> 3);
  const int ss = lane & 7;
  const _Float16* Abase = A + (size_t)m0 * Kdim;

  auto stageA = [&](const _Float16* gsrc, int ldsBase) {
#pragma unroll
    for (int round = 0; round < 2; ++round) {
      int r = (round << 6) + srr;
      int c = ss ^ (r & 7);
      gload_lds16(gsrc + (size_t)r * Kdim + (c << 3),
                  lds + ldsBase + (round << 13) + (wid << 10));
    }
  };

  // B per-lane row pointers: row = g*64 + wn*16 + l15, k-slice lq*8 baked in.
  const _Float16* Bpanel = BT + (size_t)(wg & 15) * 192 * Kdim;
  const _Float16* pB[3];
#pragma unroll
  for (int g = 0; g < 3; ++g)
    pB[g] = Bpanel + (size_t)(g * 64 + wn * 16 + l15) * Kdim + lq * 8;

  floatx4 acc[4][3] = {};

  // prologue: A(0)->buf0, A(1)->buf1
  stageA(Abase, 0);
  stageA(Abase + GBK, LBUF);
  asm volatile("s_waitcnt vmcnt(2)" ::: "memory");  // A(0) landed
  __builtin_amdgcn_s_barrier();

  for (int kt = 0; kt < NT; ++kt) {
    const int cur = (kt & 1) * LBUF;

    // ---- B fragment loads (6 x dwordx4, L2-hot) issued at tile head
    half8 b[3][2];
#pragma unroll
    for (int g = 0; g < 3; ++g)
#pragma unroll
      for (int ks = 0; ks < 2; ++ks)
        b[g][ks] = *(const half8*)(pB[g] + kt * GBK + (ks << 5));

    // ---- A fragment reads from LDS (8 x ds_read_b128)
    half8 a[4][2];
#pragma unroll
    for (int mi = 0; mi < 4; ++mi)
#pragma unroll
      for (int ks = 0; ks < 2; ++ks)
        a[mi][ks] = *(const half8*)(lds + cur + (aO[mi] ^ (ks << 6)));

    // ---- Q0: mi 0..1 (12 MFMA); compiler waits lgkm(a) + vmcnt(b) here.
    // The b-wait transitively retires this wave's A(kt+1) stage (FIFO).
    __builtin_amdgcn_s_setprio(1);
#pragma unroll
    for (int ks = 0; ks < 2; ++ks)
#pragma unroll
      for (int mi = 0; mi < 2; ++mi)
#pragma unroll
        for (int g = 0; g < 3; ++g)
          acc[mi][g] = __builtin_amdgcn_mfma_f32_16x16x32_f16(
              a[mi][ks], b[g][ks], acc[mi][g], 0, 0, 0);
    __builtin_amdgcn_s_setprio(0);

    // single barrier per tile: all waves past Q0 => (i) every wave's cur-A
    // reads are done (cur-A dead, safe to restage); (ii) every wave's
    // A(kt+1) stage has retired (next tile's reads are safe).
    __builtin_amdgcn_s_barrier();
    if (kt + 2 < NT) stageA(Abase + (kt + 2) * GBK, cur);

    // ---- Q1: mi 2..3 (12 MFMA, frags already in regs)
    __builtin_amdgcn_s_setprio(1);
#pragma unroll
    for (int ks = 0; ks < 2; ++ks)
#pragma unroll
      for (int mi = 2; mi < 4; ++mi)
#pragma unroll
        for (int g = 0; g < 3; ++g)
          acc[mi][g] = __builtin_amdgcn_mfma_f32_16x16x32_f16(
              a[mi][ks], b[g][ks], acc[mi][g], 0, 0, 0);
    __builtin_amdgcn_s_setprio(0);
  }

  // epilogue: D layout col=l15, row=lq*4+r. Lane holds f,i,h for ONE d-channel
  // and 4 consecutive steps; frag's 16 rows = one chunk. Write packed (f,v)
  // fp16 and compose the chunk aggregate via 4-lane shfl.
  const int dcol = d0 + wn * 16 + l15;
#pragma unroll
  for (int mf = 0; mf < 4; ++mf) {
    int row0 = m0 + wm * 64 + mf * 16;  // chunk-aligned
    float Fl = 1.f, Hl = 0.f;
#pragma unroll
    for (int r = 0; r < 4; ++r) {
      float fw, v;
      gate_fv(acc[mf][0][r], acc[mf][1][r], acc[mf][2][r], fw, v);
      half2v o = {(_Float16)fw, (_Float16)v};
      *(half2v*)(fv + ((size_t)(row0 + (lq << 2) + r) * Dd + dcol) * 2) = o;
      float fr = (float)o[0], vr = (float)o[1];  // rounded = replay-consistent
      Hl = fmaf(fr, Hl, vr);
      Fl *= fr;
    }
    float Fg = 1.f, Hg = 0.f;
#pragma unroll
    for (int j = 0; j < 4; ++j) {
      float Fj = __shfl(Fl, j * 16 + l15);
      float Hj = __shfl(Hl, j * 16 + l15);
      Hg = fmaf(Fj, Hg, Hj);
      Fg *= Fj;
    }
    if (lq == 0) {
      int bb = row0 >> 12, s0 = row0 & (Ss - 1);
      int co = (bb * CH + (s0 >> 4)) * Dd + dcol;
      Fc[co] = Fg;
      Hc[co] = Hg;
    }
  }
}

// ---------------------------------------------------------------- K4: chunk-carry scan (tiny)
__global__ __launch_bounds__(256) void scan2_k(const float* __restrict__ Fc,
                                               const float* __restrict__ Hc,
                                               float* __restrict__ Carry) {
  int idx = blockIdx.x * 256 + threadIdx.x;  // 0..4095
  int b = idx >> 10, d = idx & (Dd - 1);
  float carry = 0.f;
#pragma unroll 8
  for (int c = 0; c < CH; ++c) {
    int co = (b * CH + c) * Dd + d;
    Carry[co] = carry;
    carry = fmaf(Fc[co], carry, Hc[co]);
  }
}

// ---------------------------------------------------------------- K5: replay from packed fv with carry, write fp32
__global__ __launch_bounds__(256) void scan3_k(const _Float16* __restrict__ fv,
                                               const float* __restrict__ Carry,
                                               float* __restrict__ Out) {
  int d = threadIdx.x * 4;
  int c = blockIdx.y, b = blockIdx.z;
  int64_t m0 = (int64_t)(b * Ss + c * LCH);
  const _Float16* p = fv + (m0 * Dd + d) * 2;
  float* o = Out + m0 * Dd + d;
  int co = (b * CH + c) * Dd + d;
  floatx4 hv = *(const floatx4*)(Carry + co);
  float h[4] = {hv[0], hv[1], hv[2], hv[3]};
#pragma unroll 4
  for (int s = 0; s < LCH; ++s) {
    half8 q = *(const half8*)p;
#pragma unroll
    for (int j = 0; j < 4; ++j)
      h[j] = fmaf((float)q[2 * j], h[j], (float)q[2 * j + 1]);
    *(floatx4*)o = *(floatx4*)h;
    p += Dd * 2;
    o += Dd;
  }
}

// ---------------------------------------------------------------- launch
extern "C" void kernel_launch(void* const* d_in, const int* in_sizes, int n_in,
                              void* d_out, int out_size, void* d_ws, size_t ws_size,
                              hipStream_t stream) {
  const float* x = (const float*)d_in[0];   // [B,S,D] fp32
  const float* W = (const float*)d_in[1];   // [D,3D] fp32
  float* out = (float*)d_out;               // [B,S,D] fp32

  char* ws = (char*)d_ws;
  size_t off = 0;
  auto alloc = [&](size_t bytes) {
    char* p = ws + off;
    off += (bytes + 255) & ~size_t(255);
    return p;
  };
  _Float16* fv     = (_Float16*)alloc((size_t)Mdim * Dd * 2 * 2);     // 64 MiB
  float* Fc        = (float*)alloc((size_t)Bb * CH * Dd * 4);         // 4 MiB
  float* Hc        = (float*)alloc((size_t)Bb * CH * Dd * 4);
  float* Carry     = (float*)alloc((size_t)Bb * CH * Dd * 4);
  _Float16* x16    = (_Float16*)alloc((size_t)Mdim * Kdim * 2);       // 32 MiB
  _Float16* w16t   = (_Float16*)alloc((size_t)Ndim * Kdim * 2);       // 6 MiB
  if (off > ws_size) return;  // workspace too small: fail cleanly

  cvt_k<<<5120, 256, 0, stream>>>(x, x16, W, w16t);
  gemm8_k<<<dim3((Mdim / GBM) * (Dd / 64)), 512, 32768, stream>>>(x16, w16t, fv, Fc, Hc);
  scan2_k<<<(Bb * Dd) / 256, 256, 0, stream>>>(Fc, Hc, Carry);
  scan3_k<<<dim3(1, CH, Bb), 256, 0, stream>>>(fv, Carry, out);
}

// Round 16
// 174.520 us; speedup vs baseline: 1.5364x; 1.5364x over previous
//
#include <hip/hip_runtime.h>
#include <hip/hip_fp16.h>
#include <cstdint>

typedef _Float16 half8  __attribute__((ext_vector_type(8)));
typedef _Float16 half4v __attribute__((ext_vector_type(4)));
typedef _Float16 half2v __attribute__((ext_vector_type(2)));
typedef float    floatx4 __attribute__((ext_vector_type(4)));

// problem dims (fixed by setup_inputs)
constexpr int Bb = 4, Ss = 4096, Dd = 1024;
constexpr int Mdim = Bb * Ss;          // 16384
constexpr int Ndim = 3 * Dd;           // 3072
constexpr int Kdim = Dd;               // 1024
constexpr int CH = 256, LCH = Ss / CH; // 256 chunks of 16 steps (= MFMA frag M)

// fv layout: [M/4][D][8] fp16 — pack p=row>>2 holds {f,v}x4 steps for one
// d-channel, so the GEMM epilogue stores one half8 per fragment per lane and
// scan3 reads 16 B/lane coalesced.

// ---------------------------------------------------------------- utils
__device__ __forceinline__ void gload_lds16(const void* g, void* l) {
  __builtin_amdgcn_global_load_lds(
      (const __attribute__((address_space(1))) uint32_t*)g,
      (__attribute__((address_space(3))) uint32_t*)l, 16, 0, 0);
}

// gate math: fw = sig(f)/(sig(f)+sig(i)) = (1+e^-i)/(2+e^-f+e^-i)
//            iw = (1+e^-f)/(2+e^-f+e^-i);  v = iw * g~(h)
__device__ __forceinline__ void gate_fv(float fg, float ig, float hg,
                                        float& fw, float& v) {
  float ef = __expf(fminf(-fg, 40.f));
  float ei = __expf(fminf(-ig, 40.f));
  float r  = __builtin_amdgcn_rcpf(2.f + ef + ei);
  fw = (1.f + ei) * r;
  float iw = (1.f + ef) * r;
  float g  = hg >= 0.f ? hg + 0.5f
                       : __builtin_amdgcn_rcpf(1.f + __expf(fminf(-hg, 40.f)));
  v = iw * g;
}

// ---------------------------------------------------------------- K0: fused x->fp16 + W transpose->fp16 (permuted)
// p(n) = (d>>6)*192 + g*64 + (d&63): each GEMM n-block gets contiguous rows
// {f,i,h} for its 64 d-channels.
__global__ __launch_bounds__(256) void cvt_k(const float* __restrict__ X,
                                             _Float16* __restrict__ X16,
                                             const float* __restrict__ W,
                                             _Float16* __restrict__ WT) {
  __shared__ float tile[32][33];
  int bid = blockIdx.x;
  if (bid < 2048) {
    const int n4 = Mdim * Kdim / 4;
    for (int i = bid * 256 + threadIdx.x; i < n4; i += 2048 * 256) {
      float4 v = ((const float4*)X)[i];
      half4v o = {(_Float16)v.x, (_Float16)v.y, (_Float16)v.z, (_Float16)v.w};
      ((half4v*)X16)[i] = o;
    }
  } else {
    int b2 = bid - 2048;
    int tx = threadIdx.x & 31, ty = threadIdx.x >> 5;  // 32 x 8
    int n0 = (b2 % 96) * 32, k0 = (b2 / 96) * 32;
#pragma unroll
    for (int j = 0; j < 4; ++j) {
      int k = ty + j * 8;
      tile[k][tx] = W[(int64_t)(k0 + k) * Ndim + n0 + tx];
    }
    __syncthreads();
#pragma unroll
    for (int j = 0; j < 4; ++j) {
      int nl = ty + j * 8;
      int n = n0 + nl;
      int g = n >> 10, d = n & 1023;
      int p = (d >> 6) * 192 + g * 64 + (d & 63);
      WT[(int64_t)p * Kdim + k0 + tx] = (_Float16)tile[tx][nl];
    }
  }
}

// ---------------------------------------------------------------- K1: 128x192 GEMM + fused gate + chunk-aggregate epilogue
// (R12 schedule, verified local optimum: 80 KiB LDS -> 2 blocks/CU, 2-tile
// prefetch, boundary vmcnt(5), XOR-swizzled A/B in LDS.)
constexpr int GBM = 128, GBN = 192, GBK = 64;
constexpr int NT = Kdim / GBK;  // 16 K-tiles
constexpr int LBUF = 40960;

__global__ __launch_bounds__(512, 4) void gemm8_k(const _Float16* __restrict__ A,
                                                  const _Float16* __restrict__ BT,
                                                  _Float16* __restrict__ fv,
                                                  float* __restrict__ Fc,
                                                  float* __restrict__ Hc) {
  extern __shared__ char lds[];  // 81920 bytes
  const int tid = threadIdx.x;
  const int wid = tid >> 6, lane = tid & 63;
  const int wm = wid >> 2, wn = wid & 3;  // 2 M-groups x 4 N-groups
  const int l15 = lane & 15, lq = lane >> 4;

  // XCD-aware swizzle (2048 % 8 == 0 -> bijective)
  int wg = blockIdx.x;
  wg = (wg & 7) * 256 + (wg >> 3);
  const int m0 = (wg >> 4) * GBM;       // 128 m-panels
  const int d0 = (wg & 15) * 64;        // 16 d-panels

  // LDS read byte-offsets (ks=0); ks=1 = offset ^ 64 (XOR-swizzle property)
  int aO[4];
#pragma unroll
  for (int mi = 0; mi < 4; ++mi) {
    int r = wm * 64 + mi * 16 + l15;
    aO[mi] = r * 128 + ((lq ^ (r & 7)) << 4);
  }
  const int rB = wn * 16 + l15;  // same local row for all 3 gates
  const int bO = rB * 128 + ((lq ^ (rB & 7)) << 4);

  // staging: thread -> (row srr + 64*round, slot ss); dest linear,
  // source column pre-inverse-swizzled (rule #21)
  const int srr = (wid << 3) + (lane >> 3);
  const int ss = lane & 7;
  const _Float16* Abase = A + (size_t)m0 * Kdim;
  const _Float16* Bbase = BT + (size_t)(wg & 15) * 192 * Kdim;

  auto stage = [&](const _Float16* gsrc, int ldsBase, int nr) {
#pragma unroll
    for (int round = 0; round < 3; ++round) {
      if (round >= nr) break;
      int r = (round << 6) + srr;
      int c = ss ^ (r & 7);
      gload_lds16(gsrc + (size_t)r * Kdim + (c << 3),
                  lds + ldsBase + (round << 13) + (wid << 10));
    }
  };

  floatx4 acc[4][3] = {};

  // prologue: tile0 -> buf0, tile1 -> buf1 (5 loads each)
  stage(Abase, 0, 2);
  stage(Bbase, 16384, 3);
  stage(Abase + 64, LBUF, 2);
  stage(Bbase + 64, LBUF + 16384, 3);
  asm volatile("s_waitcnt vmcnt(5)" ::: "memory");  // tile0 landed
  __builtin_amdgcn_s_barrier();

  for (int kt = 0; kt < NT; ++kt) {
    const int cur = (kt & 1) * LBUF;

    half8 a[4][2], b[3][2];
    // ---- head reads: a first, then b => b[2][1] is last-issued; consuming
    // it in Q0 drains ALL head reads (in-order LDS) before the mid-barrier.
#pragma unroll
    for (int mi = 0; mi < 4; ++mi)
#pragma unroll
      for (int ks = 0; ks < 2; ++ks)
        a[mi][ks] = *(const half8*)(lds + cur + (aO[mi] ^ (ks << 6)));
#pragma unroll
    for (int g = 0; g < 3; ++g)
#pragma unroll
      for (int ks = 0; ks < 2; ++ks)
        b[g][ks] = *(const half8*)(lds + cur + 16384 + (g << 13) + (bO ^ (ks << 6)));

    // ---- Q0: mi 0..1, all g, all ks (12 MFMA) — consumes every b frag
    __builtin_amdgcn_s_setprio(1);
#pragma unroll
    for (int ks = 0; ks < 2; ++ks)
#pragma unroll
      for (int mi = 0; mi < 2; ++mi)
#pragma unroll
        for (int g = 0; g < 3; ++g)
          acc[mi][g] = __builtin_amdgcn_mfma_f32_16x16x32_f16(
              a[mi][ks], b[g][ks], acc[mi][g], 0, 0, 0);
    __builtin_amdgcn_s_setprio(0);

    // mid barrier: all waves' 14 head reads complete -> cur regions dead
    __builtin_amdgcn_s_barrier();
    if (kt + 2 < NT) {
      const _Float16* Ak = Abase + (kt + 2) * GBK;
      const _Float16* Bk = Bbase + (kt + 2) * GBK;
      stage(Ak, cur, 2);           // A(kt+2) over dead cur-A
      stage(Bk, cur + 16384, 3);   // B(kt+2) over dead cur-B
    }

    // ---- Q1: mi 2..3 (12 MFMA, frags already in regs)
    __builtin_amdgcn_s_setprio(1);
#pragma unroll
    for (int ks = 0; ks < 2; ++ks)
#pragma unroll
      for (int mi = 2; mi < 4; ++mi)
#pragma unroll
        for (int g = 0; g < 3; ++g)
          acc[mi][g] = __builtin_amdgcn_mfma_f32_16x16x32_f16(
              a[mi][ks], b[g][ks], acc[mi][g], 0, 0, 0);
    __builtin_amdgcn_s_setprio(0);

    // K-tile boundary: counted vmcnt (never 0 mid-loop), then barrier
    if (kt < NT - 2) {
      asm volatile("s_waitcnt vmcnt(5)" ::: "memory");  // kt+1 landed, kt+2 in flight
      __builtin_amdgcn_s_barrier();
    } else if (kt == NT - 2) {
      asm volatile("s_waitcnt vmcnt(0)" ::: "memory");  // drain: no stages left
      __builtin_amdgcn_s_barrier();
    }
  }

  // epilogue: D layout col=l15, row=lq*4+r. Lane holds f,i,h for ONE d-channel
  // and 4 consecutive steps (one fv pack); frag's 16 rows = one chunk.
  // One half8 store per frag; chunk aggregate composed via 4-lane shfl.
  const int dcol = d0 + wn * 16 + l15;
#pragma unroll
  for (int mf = 0; mf < 4; ++mf) {
    int row0 = m0 + wm * 64 + mf * 16;  // chunk-aligned
    float Fl = 1.f, Hl = 0.f;
    half8 o;
#pragma unroll
    for (int r = 0; r < 4; ++r) {
      float fw, v;
      gate_fv(acc[mf][0][r], acc[mf][1][r], acc[mf][2][r], fw, v);
      o[2 * r] = (_Float16)fw;
      o[2 * r + 1] = (_Float16)v;
      float fr = (float)o[2 * r], vr = (float)o[2 * r + 1];  // rounded
      Hl = fmaf(fr, Hl, vr);
      Fl *= fr;
    }
    *(half8*)(fv + ((size_t)((row0 >> 2) + lq) * Dd + dcol) * 8) = o;
    float Fg = 1.f, Hg = 0.f;
#pragma unroll
    for (int j = 0; j < 4; ++j) {
      float Fj = __shfl(Fl, j * 16 + l15);
      float Hj = __shfl(Hl, j * 16 + l15);
      Hg = fmaf(Fj, Hg, Hj);
      Fg *= Fj;
    }
    if (lq == 0) {
      int bb = row0 >> 12, s0 = row0 & (Ss - 1);
      int co = (bb * CH + (s0 >> 4)) * Dd + dcol;
      Fc[co] = Fg;
      Hc[co] = Hg;
    }
  }
}

// ---------------------------------------------------------------- K4: chunk-carry scan (tiny)
__global__ __launch_bounds__(256) void scan2_k(const float* __restrict__ Fc,
                                               const float* __restrict__ Hc,
                                               float* __restrict__ Carry) {
  int idx = blockIdx.x * 256 + threadIdx.x;  // 0..4095
  int b = idx >> 10, d = idx & (Dd - 1);
  float carry = 0.f;
#pragma unroll 8
  for (int c = 0; c < CH; ++c) {
    int co = (b * CH + c) * Dd + d;
    Carry[co] = carry;
    carry = fmaf(Fc[co], carry, Hc[co]);
  }
}

// ---------------------------------------------------------------- K5: replay from packed fv with carry, write fp32
// 1 d-channel per thread; 4 half8 loads (16 B/lane, coalesced) per chunk.
__global__ __launch_bounds__(256) void scan3_k(const _Float16* __restrict__ fv,
                                               const float* __restrict__ Carry,
                                               float* __restrict__ Out) {
  int d = blockIdx.x * 256 + threadIdx.x;  // 0..1023
  int c = blockIdx.y, b = blockIdx.z;
  int row0 = b * Ss + c * LCH;
  const _Float16* p = fv + ((size_t)(row0 >> 2) * Dd + d) * 8;
  float* o = Out + (size_t)row0 * Dd + d;
  float h = Carry[(b * CH + c) * Dd + d];
#pragma unroll
  for (int j = 0; j < 4; ++j) {          // 4 packs of 4 steps
    half8 q = *(const half8*)(p + (size_t)j * Dd * 8);
#pragma unroll
    for (int r = 0; r < 4; ++r) {
      h = fmaf((float)q[2 * r], h, (float)q[2 * r + 1]);
      o[(size_t)(j * 4 + r) * Dd] = h;
    }
  }
}

// ---------------------------------------------------------------- launch
extern "C" void kernel_launch(void* const* d_in, const int* in_sizes, int n_in,
                              void* d_out, int out_size, void* d_ws, size_t ws_size,
                              hipStream_t stream) {
  const float* x = (const float*)d_in[0];   // [B,S,D] fp32
  const float* W = (const float*)d_in[1];   // [D,3D] fp32
  float* out = (float*)d_out;               // [B,S,D] fp32

  char* ws = (char*)d_ws;
  size_t off = 0;
  auto alloc = [&](size_t bytes) {
    char* p = ws + off;
    off += (bytes + 255) & ~size_t(255);
    return p;
  };
  _Float16* fv     = (_Float16*)alloc((size_t)Mdim * Dd * 2 * 2);     // 64 MiB
  float* Fc        = (float*)alloc((size_t)Bb * CH * Dd * 4);         // 4 MiB
  float* Hc        = (float*)alloc((size_t)Bb * CH * Dd * 4);
  float* Carry     = (float*)alloc((size_t)Bb * CH * Dd * 4);
  _Float16* x16    = (_Float16*)alloc((size_t)Mdim * Kdim * 2);       // 32 MiB
  _Float16* w16t   = (_Float16*)alloc((size_t)Ndim * Kdim * 2);       // 6 MiB
  if (off > ws_size) return;  // workspace too small: fail cleanly

  cvt_k<<<5120, 256, 0, stream>>>(x, x16, W, w16t);
  gemm8_k<<<dim3((Mdim / GBM) * (Dd / 64)), 512, 81920, stream>>>(x16, w16t, fv, Fc, Hc);
  scan2_k<<<(Bb * Dd) / 256, 256, 0, stream>>>(Fc, Hc, Carry);
  scan3_k<<<dim3(4, CH, Bb), 256, 0, stream>>>(fv, Carry, out);
}

// Round 17
// 171.827 us; speedup vs baseline: 1.5605x; 1.0157x over previous
//
#include <hip/hip_runtime.h>
#include <hip/hip_fp16.h>
#include <cstdint>

typedef _Float16 half8  __attribute__((ext_vector_type(8)));
typedef _Float16 half4v __attribute__((ext_vector_type(4)));
typedef _Float16 half2v __attribute__((ext_vector_type(2)));
typedef float    floatx4 __attribute__((ext_vector_type(4)));

// problem dims (fixed by setup_inputs)
constexpr int Bb = 4, Ss = 4096, Dd = 1024;
constexpr int Mdim = Bb * Ss;          // 16384
constexpr int Ndim = 3 * Dd;           // 3072
constexpr int Kdim = Dd;               // 1024
constexpr int CH = 256, LCH = Ss / CH; // 256 chunks of 16 steps (= MFMA frag M)

// fv layout: [M/4][D][8] fp16 — pack p=row>>2 holds {f,v}x4 steps for one
// d-channel: GEMM epilogue stores one half8/frag/lane; scan3 reads 16 B/lane.

// ---------------------------------------------------------------- utils
__device__ __forceinline__ void gload_lds16(const void* g, void* l) {
  __builtin_amdgcn_global_load_lds(
      (const __attribute__((address_space(1))) uint32_t*)g,
      (__attribute__((address_space(3))) uint32_t*)l, 16, 0, 0);
}

// gate math: fw = sig(f)/(sig(f)+sig(i)) = (1+e^-i)/(2+e^-f+e^-i)
//            iw = (1+e^-f)/(2+e^-f+e^-i);  v = iw * g~(h)
__device__ __forceinline__ void gate_fv(float fg, float ig, float hg,
                                        float& fw, float& v) {
  float ef = __expf(fminf(-fg, 40.f));
  float ei = __expf(fminf(-ig, 40.f));
  float r  = __builtin_amdgcn_rcpf(2.f + ef + ei);
  fw = (1.f + ei) * r;
  float iw = (1.f + ef) * r;
  float g  = hg >= 0.f ? hg + 0.5f
                       : __builtin_amdgcn_rcpf(1.f + __expf(fminf(-hg, 40.f)));
  v = iw * g;
}

// ---------------------------------------------------------------- K0: fused x->fp16 + W transpose->fp16 (permuted)
// p(n) = (d>>6)*192 + g*64 + (d&63): each GEMM n-block gets contiguous rows
// {f,i,h} for its 64 d-channels.
__global__ __launch_bounds__(256) void cvt_k(const float* __restrict__ X,
                                             _Float16* __restrict__ X16,
                                             const float* __restrict__ W,
                                             _Float16* __restrict__ WT) {
  __shared__ float tile[32][33];
  int bid = blockIdx.x;
  if (bid < 2048) {
    const int n4 = Mdim * Kdim / 4;
    for (int i = bid * 256 + threadIdx.x; i < n4; i += 2048 * 256) {
      float4 v = ((const float4*)X)[i];
      half4v o = {(_Float16)v.x, (_Float16)v.y, (_Float16)v.z, (_Float16)v.w};
      ((half4v*)X16)[i] = o;
    }
  } else {
    int b2 = bid - 2048;
    int tx = threadIdx.x & 31, ty = threadIdx.x >> 5;  // 32 x 8
    int n0 = (b2 % 96) * 32, k0 = (b2 / 96) * 32;
#pragma unroll
    for (int j = 0; j < 4; ++j) {
      int k = ty + j * 8;
      tile[k][tx] = W[(int64_t)(k0 + k) * Ndim + n0 + tx];
    }
    __syncthreads();
#pragma unroll
    for (int j = 0; j < 4; ++j) {
      int nl = ty + j * 8;
      int n = n0 + nl;
      int g = n >> 10, d = n & 1023;
      int p = (d >> 6) * 192 + g * 64 + (d & 63);
      WT[(int64_t)p * Kdim + k0 + tx] = (_Float16)tile[tx][nl];
    }
  }
}

// ---------------------------------------------------------------- K1: 128x192 GEMM + fused gate + chunk-aggregate epilogue
// (R12 schedule: 80 KiB LDS -> 2 blocks/CU, 2-tile prefetch, boundary
// vmcnt(5), XOR-swizzled A/B in LDS.)  NEW: L2-locality window remap —
// each XCD's contiguous 64-wg active window spans 8 m-panels x 8 d-panels
// (A 2 MiB + B 3 MiB ~ L2-fit) instead of 4x16 (B 6 MiB thrashes).
constexpr int GBM = 128, GBN = 192, GBK = 64;
constexpr int NT = Kdim / GBK;  // 16 K-tiles
constexpr int LBUF = 40960;

__global__ __launch_bounds__(512, 4) void gemm8_k(const _Float16* __restrict__ A,
                                                  const _Float16* __restrict__ BT,
                                                  _Float16* __restrict__ fv,
                                                  float* __restrict__ Fc,
                                                  float* __restrict__ Hc) {
  extern __shared__ char lds[];  // 81920 bytes
  const int tid = threadIdx.x;
  const int wid = tid >> 6, lane = tid & 63;
  const int wm = wid >> 2, wn = wid & 3;  // 2 M-groups x 4 N-groups
  const int l15 = lane & 15, lq = lane >> 4;

  // XCD-aware swizzle (2048 % 8 == 0 -> bijective), then 8m x 8d windows
  int wg = blockIdx.x;
  wg = (wg & 7) * 256 + (wg >> 3);      // per-XCD contiguous chunk of 256
  const int win = wg >> 6;              // [0,32) = 16 m-super x 2 d-super
  const int wi = wg & 63;               // 8 m x 8 d within window
  const int m0 = (((win >> 1) << 3) + (wi >> 3)) * GBM;  // 128 m-panels
  const int dp = ((win & 1) << 3) + (wi & 7);            // 16 d-panels
  const int d0 = dp * 64;

  // LDS read byte-offsets (ks=0); ks=1 = offset ^ 64 (XOR-swizzle property)
  int aO[4];
#pragma unroll
  for (int mi = 0; mi < 4; ++mi) {
    int r = wm * 64 + mi * 16 + l15;
    aO[mi] = r * 128 + ((lq ^ (r & 7)) << 4);
  }
  const int rB = wn * 16 + l15;  // same local row for all 3 gates
  const int bO = rB * 128 + ((lq ^ (rB & 7)) << 4);

  // staging: thread -> (row srr + 64*round, slot ss); dest linear,
  // source column pre-inverse-swizzled (rule #21)
  const int srr = (wid << 3) + (lane >> 3);
  const int ss = lane & 7;
  const _Float16* Abase = A + (size_t)m0 * Kdim;
  const _Float16* Bbase = BT + (size_t)dp * 192 * Kdim;

  auto stage = [&](const _Float16* gsrc, int ldsBase, int nr) {
#pragma unroll
    for (int round = 0; round < 3; ++round) {
      if (round >= nr) break;
      int r = (round << 6) + srr;
      int c = ss ^ (r & 7);
      gload_lds16(gsrc + (size_t)r * Kdim + (c << 3),
                  lds + ldsBase + (round << 13) + (wid << 10));
    }
  };

  floatx4 acc[4][3] = {};

  // prologue: tile0 -> buf0, tile1 -> buf1 (5 loads each)
  stage(Abase, 0, 2);
  stage(Bbase, 16384, 3);
  stage(Abase + 64, LBUF, 2);
  stage(Bbase + 64, LBUF + 16384, 3);
  asm volatile("s_waitcnt vmcnt(5)" ::: "memory");  // tile0 landed
  __builtin_amdgcn_s_barrier();

  for (int kt = 0; kt < NT; ++kt) {
    const int cur = (kt & 1) * LBUF;

    half8 a[4][2], b[3][2];
    // ---- head reads: a first, then b => b[2][1] is last-issued; consuming
    // it in Q0 drains ALL head reads (in-order LDS) before the mid-barrier.
#pragma unroll
    for (int mi = 0; mi < 4; ++mi)
#pragma unroll
      for (int ks = 0; ks < 2; ++ks)
        a[mi][ks] = *(const half8*)(lds + cur + (aO[mi] ^ (ks << 6)));
#pragma unroll
    for (int g = 0; g < 3; ++g)
#pragma unroll
      for (int ks = 0; ks < 2; ++ks)
        b[g][ks] = *(const half8*)(lds + cur + 16384 + (g << 13) + (bO ^ (ks << 6)));

    // ---- Q0: mi 0..1, all g, all ks (12 MFMA) — consumes every b frag
    __builtin_amdgcn_s_setprio(1);
#pragma unroll
    for (int ks = 0; ks < 2; ++ks)
#pragma unroll
      for (int mi = 0; mi < 2; ++mi)
#pragma unroll
        for (int g = 0; g < 3; ++g)
          acc[mi][g] = __builtin_amdgcn_mfma_f32_16x16x32_f16(
              a[mi][ks], b[g][ks], acc[mi][g], 0, 0, 0);
    __builtin_amdgcn_s_setprio(0);

    // mid barrier: all waves' 14 head reads complete -> cur regions dead
    __builtin_amdgcn_s_barrier();
    if (kt + 2 < NT) {
      const _Float16* Ak = Abase + (kt + 2) * GBK;
      const _Float16* Bk = Bbase + (kt + 2) * GBK;
      stage(Ak, cur, 2);           // A(kt+2) over dead cur-A
      stage(Bk, cur + 16384, 3);   // B(kt+2) over dead cur-B
    }

    // ---- Q1: mi 2..3 (12 MFMA, frags already in regs)
    __builtin_amdgcn_s_setprio(1);
#pragma unroll
    for (int ks = 0; ks < 2; ++ks)
#pragma unroll
      for (int mi = 2; mi < 4; ++mi)
#pragma unroll
        for (int g = 0; g < 3; ++g)
          acc[mi][g] = __builtin_amdgcn_mfma_f32_16x16x32_f16(
              a[mi][ks], b[g][ks], acc[mi][g], 0, 0, 0);
    __builtin_amdgcn_s_setprio(0);

    // K-tile boundary: counted vmcnt (never 0 mid-loop), then barrier
    if (kt < NT - 2) {
      asm volatile("s_waitcnt vmcnt(5)" ::: "memory");  // kt+1 landed, kt+2 in flight
      __builtin_amdgcn_s_barrier();
    } else if (kt == NT - 2) {
      asm volatile("s_waitcnt vmcnt(0)" ::: "memory");  // drain: no stages left
      __builtin_amdgcn_s_barrier();
    }
  }

  // epilogue: D layout col=l15, row=lq*4+r. Lane holds f,i,h for ONE d-channel
  // and 4 consecutive steps (one fv pack); frag's 16 rows = one chunk.
  // One half8 store per frag; chunk aggregate composed via 4-lane shfl.
  const int dcol = d0 + wn * 16 + l15;
#pragma unroll
  for (int mf = 0; mf < 4; ++mf) {
    int row0 = m0 + wm * 64 + mf * 16;  // chunk-aligned
    float Fl = 1.f, Hl = 0.f;
    half8 o;
#pragma unroll
    for (int r = 0; r < 4; ++r) {
      float fw, v;
      gate_fv(acc[mf][0][r], acc[mf][1][r], acc[mf][2][r], fw, v);
      o[2 * r] = (_Float16)fw;
      o[2 * r + 1] = (_Float16)v;
      float fr = (float)o[2 * r], vr = (float)o[2 * r + 1];  // rounded
      Hl = fmaf(fr, Hl, vr);
      Fl *= fr;
    }
    *(half8*)(fv + ((size_t)((row0 >> 2) + lq) * Dd + dcol) * 8) = o;
    float Fg = 1.f, Hg = 0.f;
#pragma unroll
    for (int j = 0; j < 4; ++j) {
      float Fj = __shfl(Fl, j * 16 + l15);
      float Hj = __shfl(Hl, j * 16 + l15);
      Hg = fmaf(Fj, Hg, Hj);
      Fg *= Fj;
    }
    if (lq == 0) {
      int bb = row0 >> 12, s0 = row0 & (Ss - 1);
      int co = (bb * CH + (s0 >> 4)) * Dd + dcol;
      Fc[co] = Fg;
      Hc[co] = Hg;
    }
  }
}

// ---------------------------------------------------------------- K4: chunk-carry scan (tiny)
__global__ __launch_bounds__(256) void scan2_k(const float* __restrict__ Fc,
                                               const float* __restrict__ Hc,
                                               float* __restrict__ Carry) {
  int idx = blockIdx.x * 256 + threadIdx.x;  // 0..4095
  int b = idx >> 10, d = idx & (Dd - 1);
  float carry = 0.f;
#pragma unroll 8
  for (int c = 0; c < CH; ++c) {
    int co = (b * CH + c) * Dd + d;
    Carry[co] = carry;
    carry = fmaf(Fc[co], carry, Hc[co]);
  }
}

// ---------------------------------------------------------------- K5: replay from packed fv with carry, write fp32
// 1 d-channel per thread; 4 half8 loads (16 B/lane, coalesced) per chunk.
__global__ __launch_bounds__(256) void scan3_k(const _Float16* __restrict__ fv,
                                               const float* __restrict__ Carry,
                                               float* __restrict__ Out) {
  int d = blockIdx.x * 256 + threadIdx.x;  // 0..1023
  int c = blockIdx.y, b = blockIdx.z;
  int row0 = b * Ss + c * LCH;
  const _Float16* p = fv + ((size_t)(row0 >> 2) * Dd + d) * 8;
  float* o = Out + (size_t)row0 * Dd + d;
  float h = Carry[(b * CH + c) * Dd + d];
#pragma unroll
  for (int j = 0; j < 4; ++j) {          // 4 packs of 4 steps
    half8 q = *(const half8*)(p + (size_t)j * Dd * 8);
#pragma unroll
    for (int r = 0; r < 4; ++r) {
      h = fmaf((float)q[2 * r], h, (float)q[2 * r + 1]);
      o[(size_t)(j * 4 + r) * Dd] = h;
    }
  }
}

// ---------------------------------------------------------------- launch
extern "C" void kernel_launch(void* const* d_in, const int* in_sizes, int n_in,
                              void* d_out, int out_size, void* d_ws, size_t ws_size,
                              hipStream_t stream) {
  const float* x = (const float*)d_in[0];   // [B,S,D] fp32
  const float* W = (const float*)d_in[1];   // [D,3D] fp32
  float* out = (float*)d_out;               // [B,S,D] fp32

  char* ws = (char*)d_ws;
  size_t off = 0;
  auto alloc = [&](size_t bytes) {
    char* p = ws + off;
    off += (bytes + 255) & ~size_t(255);
    return p;
  };
  _Float16* fv     = (_Float16*)alloc((size_t)Mdim * Dd * 2 * 2);     // 64 MiB
  float* Fc        = (float*)alloc((size_t)Bb * CH * Dd * 4);         // 4 MiB
  float* Hc        = (float*)alloc((size_t)Bb * CH * Dd * 4);
  float* Carry     = (float*)alloc((size_t)Bb * CH * Dd * 4);
  _Float16* x16    = (_Float16*)alloc((size_t)Mdim * Kdim * 2);       // 32 MiB
  _Float16* w16t   = (_Float16*)alloc((size_t)Ndim * Kdim * 2);       // 6 MiB
  if (off > ws_size) return;  // workspace too small: fail cleanly

  cvt_k<<<5120, 256, 0, stream>>>(x, x16, W, w16t);
  gemm8_k<<<dim3((Mdim / GBM) * (Dd / 64)), 512, 81920, stream>>>(x16, w16t, fv, Fc, Hc);
  scan2_k<<<(Bb * Dd) / 256, 256, 0, stream>>>(Fc, Hc, Carry);
  scan3_k<<<dim3(4, CH, Bb), 256, 0, stream>>>(fv, Carry, out);
}